// Round 5
// baseline (317.254 us; speedup 1.0000x reference)
//
#include <hip/hip_runtime.h>
#include <hip/hip_fp16.h>
#include <cmath>

// Problem constants (fixed by the reference)
constexpr int Bc = 2;
constexpr int Cc = 128;      // input channels
constexpr int Nc = 50000;
constexpr int Hh = 2;        // heads
constexpr int FHc = 64;      // features per head
constexpr int HF = Hh * FHc; // 128 = concat dim
constexpr int Mc = Bc * Nc;  // 100000 nodes
constexpr int Ec = 800000;   // edges

// CSR counting-sort geometry (role-A blocks of the fused kernel)
constexpr int PBLK = 200;                  // CSR partition blocks (<= 256 CUs -> co-resident)
constexpr int CHUNK = Ec / PBLK;           // 4000 edges per partition (CHUNK/4 = 1000 int4)
constexpr int KBKT = (Mc + 255) / 256;     // 391 buckets of 256 dst nodes
constexpr int GEMM_BLKS = (Mc + 63) / 64;  // 1563 GEMM tiles

#define NSLOPE_GAT 0.2f
#define NSLOPE_ACT 0.01f
#define LN_EPS 1e-5f
#define SM_EPS 1e-16f
#define LOG2E 1.4426950408889634f

// h-storage is column-swizzled: c' = (c%16)*8 + c/16  (c = canonical col)
// inverse: c = (c'%8)*16 + c'/8. Head of swizzled col c': (c'&7) >= 4.
// => any aligned group of 4 consecutive swizzled cols (one uint2 of fp16)
//    lies entirely within ONE head: head = parity of the group index c'/4.

typedef __attribute__((ext_vector_type(8))) short short8;
typedef __attribute__((ext_vector_type(4))) float f32x4;
typedef _Float16 half2v __attribute__((ext_vector_type(2)));

__device__ inline unsigned short f2bf(float f) {
    union { float f; unsigned int i; } v; v.f = f;
    unsigned int r = v.i + 0x7fffu + ((v.i >> 16) & 1u);
    return (unsigned short)(r >> 16);
}

#if __has_builtin(__builtin_amdgcn_exp2f)
#define EXP2(x) __builtin_amdgcn_exp2f(x)
#else
#define EXP2(x) __expf((x) * 0.6931471805599453f)
#endif

#if __has_builtin(__builtin_amdgcn_fdot2)
#define FDOT2(a, b, c) __builtin_amdgcn_fdot2((a), (b), (c), false)
#else
__device__ inline float FDOT2(half2v a, half2v b, float c) {
    return fmaf((float)a[0], (float)b[0], fmaf((float)a[1], (float)b[1], c));
}
#endif

// One v_add_f32 + DPP row-rotate step (rows of 16 lanes, all lanes active).
template <int CTRL>
__device__ inline float dpp_add_step(float x) {
    int y = __builtin_amdgcn_update_dpp(0, __builtin_bit_cast(int, x),
                                        CTRL, 0xF, 0xF, false);
    return x + __builtin_bit_cast(float, y);
}
// Full-row (16-lane) sum via row_ror 1,2,4,8 — every lane ends with the total.
__device__ inline float row16_sum(float x) {
    x = dpp_add_step<0x121>(x); // row_ror:1
    x = dpp_add_step<0x122>(x); // row_ror:2
    x = dpp_add_step<0x124>(x); // row_ror:4
    x = dpp_add_step<0x128>(x); // row_ror:8
    return x;
}

// Device-scope grid barrier over the PBLK CSR blocks (cooperative-groups
// pattern: release fence -> device-scope atomic arrive -> acquire spin).
// GEMM-role blocks never call this and always make forward progress, so the
// CSR blocks (200 <= 256 CUs, tiny LDS/VGPR for their phases) can always
// become co-resident: no deadlock topology.
__device__ inline void grid_barrier(int* bar, int target) {
    __syncthreads();
    if (threadIdx.x == 0) {
        __threadfence();                       // release: L2 writeback, device scope
        atomicAdd(bar, 1);                     // device-scope by default on global
        while (__hip_atomic_load(bar, __ATOMIC_RELAXED,
                                 __HIP_MEMORY_SCOPE_AGENT) < target)
            __builtin_amdgcn_s_sleep(16);
        __threadfence();                       // acquire: invalidate stale lines
    }
    __syncthreads();
}

// ---------------- K0: W -> B-fragment order (bf16), perm att(fp16)/bias/
//                      gamma/beta, zero the grid-barrier counter ------------
// Wb index = ((((mat*8+nt)*4+s)*64)+l)*8 + j ; holds W[k=32s+8*(l>>4)+j][n=16nt+(l&15)]
__global__ __launch_bounds__(256) void prep_w(
    const float* __restrict__ Wl, const float* __restrict__ Wr,
    const float* __restrict__ att, const float* __restrict__ bias,
    const float* __restrict__ gamma, const float* __restrict__ beta,
    unsigned short* __restrict__ Wb, _Float16* __restrict__ att_h,
    float* __restrict__ bias_perm, float* __restrict__ gamma_perm,
    float* __restrict__ beta_perm, int* __restrict__ bar)
{
    int i = blockIdx.x * 256 + threadIdx.x;
    if (i < 8) bar[i] = 0; // re-zero barrier counters every launch
    if (blockIdx.x == 0 && threadIdx.x < 128) {
        int cp = threadIdx.x;
        int c = (cp & 7) * 16 + (cp >> 3);          // canonical col of swizzled cp
        att_h[cp]      = (_Float16)(att[c] * LOG2E); // pre-scale for exp2
        bias_perm[cp]  = bias[c];
        gamma_perm[cp] = gamma[c];
        beta_perm[cp]  = beta[c];
    }
    if (i >= 32768) return;
    int j = i & 7, l = (i >> 3) & 63, s = (i >> 9) & 3, nt = (i >> 11) & 7, mat = (i >> 14) & 1;
    int q = l >> 4, n15 = l & 15;
    int k = 32 * s + 8 * q + j;
    int n = 16 * nt + n15;
    const float* W = mat ? Wr : Wl;
    Wb[i] = f2bf(W[k * HF + n]);
}

// ---------------- K1: fused GEMM + CSR-build ------------------------------
// blocks [0, PBLK)          : 4-phase CSR counting sort with grid barriers
// blocks [PBLK, PBLK+1563)  : one 64-row MFMA GEMM tile each (independent)
// The memory-bound GEMM tiles overlap the latency-bound CSR phases; both
// dataflows are independent until gat_fused consumes them next dispatch.
__global__ __launch_bounds__(256, 3) void gemm_csr(
    const float* __restrict__ x,
    const unsigned short* __restrict__ Wb,
    const float* __restrict__ bl, const float* __restrict__ br,
    unsigned short* __restrict__ hl, unsigned short* __restrict__ hr,
    const int* __restrict__ ei,
    int* __restrict__ counts, int* __restrict__ offmat,
    int* __restrict__ colsum, int* __restrict__ bucketBase,
    unsigned int* __restrict__ pairs,
    int* __restrict__ offs, int* __restrict__ deg,
    int* __restrict__ csr_src, int* __restrict__ bar)
{
    __shared__ __align__(16) unsigned char smem[16384];
    const int tid = threadIdx.x;

    if (blockIdx.x < PBLK) {
        // =================== CSR role ===================
        const int p = blockIdx.x;

        // --- Phase A: bucket histogram of this partition's 4000 edges
        {
            int* hist = (int*)smem;
            for (int k = tid; k < KBKT; k += 256) hist[k] = 0;
            __syncthreads();
            const int4* dsts = (const int4*)(ei + Ec + p * CHUNK);
            for (int i = tid; i < CHUNK / 4; i += 256) {
                int4 d = dsts[i];
                atomicAdd(&hist[d.x >> 8], 1);
                atomicAdd(&hist[d.y >> 8], 1);
                atomicAdd(&hist[d.z >> 8], 1);
                atomicAdd(&hist[d.w >> 8], 1);
            }
            __syncthreads();
            for (int k = tid; k < KBKT; k += 256) counts[p * KBKT + k] = hist[k];
        }
        grid_barrier(bar, PBLK);

        // --- Phase B: per-column partition scan -> offmat + colsum
        {
            int* sdata = (int*)smem;
            for (int k = p; k < KBKT; k += PBLK) {
                int v = (tid < PBLK) ? counts[tid * KBKT + k] : 0;
                sdata[tid] = v;
                __syncthreads();
                for (int off = 1; off < 256; off <<= 1) {
                    int u = (tid >= off) ? sdata[tid - off] : 0;
                    __syncthreads();
                    sdata[tid] += u;
                    __syncthreads();
                }
                if (tid < PBLK) offmat[tid * KBKT + k] = sdata[tid] - v;
                if (tid == 255) colsum[k] = sdata[255];
                __syncthreads();
            }
        }
        grid_barrier(bar, 2 * PBLK);

        // --- Phase B2: block 0 scans the 391 bucket totals -> bucketBase
        if (p == 0) {
            int* sd = (int*)smem;
            int v0 = (2 * tid < KBKT) ? colsum[2 * tid] : 0;
            int v1 = (2 * tid + 1 < KBKT) ? colsum[2 * tid + 1] : 0;
            int s = v0 + v1;
            sd[tid] = s;
            __syncthreads();
            for (int off = 1; off < 256; off <<= 1) {
                int u = (tid >= off) ? sd[tid - off] : 0;
                __syncthreads();
                sd[tid] += u;
                __syncthreads();
            }
            int excl = sd[tid] - s;
            if (2 * tid <= KBKT) bucketBase[2 * tid] = excl;
            if (2 * tid + 1 <= KBKT) bucketBase[2 * tid + 1] = excl + v0;
        }
        grid_barrier(bar, 3 * PBLK);

        // --- Phase C: scatter edges into private per-bucket windows
        {
            int* cur = (int*)smem;
            for (int k = tid; k < KBKT; k += 256)
                cur[k] = bucketBase[k] + offmat[p * KBKT + k];
            __syncthreads();
            const int4* srcs = (const int4*)(ei + p * CHUNK);
            const int4* dsts = (const int4*)(ei + Ec + p * CHUNK);
            for (int i = tid; i < CHUNK / 4; i += 256) {
                int4 s = srcs[i];
                int4 d = dsts[i];
                int p0 = atomicAdd(&cur[d.x >> 8], 1);
                pairs[p0] = ((unsigned)s.x << 8) | (unsigned)(d.x & 255);
                int p1 = atomicAdd(&cur[d.y >> 8], 1);
                pairs[p1] = ((unsigned)s.y << 8) | (unsigned)(d.y & 255);
                int p2 = atomicAdd(&cur[d.z >> 8], 1);
                pairs[p2] = ((unsigned)s.z << 8) | (unsigned)(d.z & 255);
                int p3 = atomicAdd(&cur[d.w >> 8], 1);
                pairs[p3] = ((unsigned)s.w << 8) | (unsigned)(d.w & 255);
            }
        }
        grid_barrier(bar, 4 * PBLK);

        // --- Phase D: per-bucket node histogram + scan -> offs/deg/csr_src
        {
            int* cnt = (int*)smem;
            int* scn = cnt + 256;
            int* cur = scn + 256;
            for (int b = p; b < KBKT; b += PBLK) {
                const int base = bucketBase[b];
                const int ecnt = bucketBase[b + 1] - base;
                cnt[tid] = 0;
                __syncthreads();
                for (int i = tid; i < ecnt; i += 256)
                    atomicAdd(&cnt[pairs[base + i] & 255u], 1);
                __syncthreads();
                int c = cnt[tid];
                scn[tid] = c;
                __syncthreads();
                for (int off = 1; off < 256; off <<= 1) {
                    int u = (tid >= off) ? scn[tid - off] : 0;
                    __syncthreads();
                    scn[tid] += u;
                    __syncthreads();
                }
                int excl = scn[tid] - c;
                int node = (b << 8) + tid;
                if (node < Mc) {
                    offs[node] = base + excl;
                    deg[node] = c;
                }
                cur[tid] = base + excl;
                __syncthreads();
                for (int i = tid; i < ecnt; i += 256) {
                    unsigned pr = pairs[base + i];
                    int pos = atomicAdd(&cur[pr & 255u], 1);
                    csr_src[pos] = (int)(pr >> 8);
                }
                __syncthreads();
            }
        }
        return;
    }

    // =================== GEMM role ===================
    unsigned char* As = smem; // 16 KB: [row][2*k] bf16, byte ^= (row&7)<<4 swizzle
    const int r0 = (blockIdx.x - PBLK) * 64;
    const int l = tid & 63, w = tid >> 6;
    const int m15 = l & 15, q = l >> 4;

    // --- B fragments: 16 per wave, global->VGPR once (L2-hot, 64 KB total)
    const int matw = w >> 1, ntb = 4 * (w & 1);
    const short8* __restrict__ WB = (const short8*)Wb;
    short8 bfrag[4][4]; // [i = nt offset][s = k-step]
    #pragma unroll
    for (int i = 0; i < 4; ++i)
        #pragma unroll
        for (int s = 0; s < 4; ++s)
            bfrag[i][s] = WB[(((matw * 8 + ntb + i) * 4 + s) * 64) + l];

    // --- stage A: lane = row, 4 channels/thread/pass, dword loads
    {
        const int lrow = tid & 63;          // local row
        const int cg   = (tid >> 6) * 4;    // channel group base
        const int grow = r0 + lrow;
        const unsigned int swz = (unsigned)((lrow & 7) << 4);
        const bool valid = grow < Mc;
        int b = 0, n = grow;
        if (n >= Nc) { b = 1; n -= Nc; }
        const float* xb = x + (size_t)(b * Cc) * Nc + n;
        #pragma unroll
        for (int pp = 0; pp < 8; ++pp) {
            int c = cg + 16 * pp;
            float v0 = 0.f, v1 = 0.f, v2 = 0.f, v3 = 0.f;
            if (valid) {
                const float* xp = xb + (size_t)c * Nc;
                v0 = xp[0];
                v1 = xp[Nc];
                v2 = xp[2 * (size_t)Nc];
                v3 = xp[3 * (size_t)Nc];
            }
            unsigned int d0 = (unsigned)f2bf(v0) | ((unsigned)f2bf(v1) << 16);
            unsigned int d1 = (unsigned)f2bf(v2) | ((unsigned)f2bf(v3) << 16);
            unsigned int off = (unsigned)lrow * 256 + (((unsigned)(c * 2)) ^ swz);
            *(uint2*)(As + off) = make_uint2(d0, d1);
        }
    }
    __syncthreads();

    // --- bias (canonical col = 16*nt + m15) and output base
    const float* bsrc = matw ? br : bl;
    unsigned short* __restrict__ hdst = matw ? hr : hl;
    float bv[4];
    #pragma unroll
    for (int i = 0; i < 4; ++i) bv[i] = bsrc[16 * (ntb + i) + m15];

    const unsigned int rswz = (unsigned)((m15 & 7) << 4);
    #pragma unroll
    for (int mt = 0; mt < 4; ++mt) {
        short8 af[4];
        #pragma unroll
        for (int s = 0; s < 4; ++s) {
            unsigned int off = (unsigned)(16 * mt + m15) * 256 +
                               (((unsigned)(64 * s + 16 * q)) ^ rswz);
            af[s] = *(const short8*)(As + off);
        }
        f32x4 acc[4];
        #pragma unroll
        for (int i = 0; i < 4; ++i) acc[i] = (f32x4)(0.f);
        #pragma unroll
        for (int s = 0; s < 4; ++s)
            #pragma unroll
            for (int i = 0; i < 4; ++i)
                acc[i] = __builtin_amdgcn_mfma_f32_16x16x32_bf16(af[s], bfrag[i][s], acc[i], 0, 0, 0);

        // D: row = 4q+reg (tile-local), canonical col = 16*(ntb+i)+m15
        // swizzled col' = m15*8 + ntb + i  ->  uint2 (4 fp16) per row
        #pragma unroll
        for (int reg = 0; reg < 4; ++reg) {
            int rD = r0 + 16 * mt + 4 * q + reg;
            if (rD < Mc) {
                half2v hlo = { (_Float16)(acc[0][reg] + bv[0]),
                               (_Float16)(acc[1][reg] + bv[1]) };
                half2v hhi = { (_Float16)(acc[2][reg] + bv[2]),
                               (_Float16)(acc[3][reg] + bv[3]) };
                *(uint2*)(hdst + (size_t)rD * HF + m15 * 8 + ntb) =
                    make_uint2(__builtin_bit_cast(unsigned int, hlo),
                               __builtin_bit_cast(unsigned int, hhi));
            }
        }
    }
}

// ---------------- K4: fully fused per-node logits+softmax+aggregate+LN ------
// One wave per node, TWO edges per iteration (one per 32-lane half).
// Lane t: half = t>>5 (edge select), i32 = t&31. Lane owns swizzled col
// GROUP g = ((i32&15)<<1)|(i32>>4) -> cols 4g..4g+3, all in head g&1 = i32>>4.
// So each head's 64 features live in ONE contiguous 16-lane DPP row: the
// per-head dot reduction is 4 v_add_f32+row_ror DPP ops -- no LDS, no
// shuffles in the inner loop. fp16 storage: packed v_pk_add/mul/max_f16 +
// v_dot2_f32_f16 for the dot; v_fma_mix_f32 for the f32 accumulate.
__global__ __launch_bounds__(256) void gat_fused(
    const unsigned short* __restrict__ hl, const unsigned short* __restrict__ hr,
    const int* __restrict__ csr_src,
    const int* __restrict__ offs, const int* __restrict__ deg,
    const _Float16* __restrict__ att_h, const float* __restrict__ bias_perm,
    const float* __restrict__ gamma_perm, const float* __restrict__ beta_perm,
    float* __restrict__ out)
{
    const int wv = threadIdx.x >> 6;
    const int t  = threadIdx.x & 63;
    const int d  = blockIdx.x * 4 + wv;
    if (d >= Mc) return;
    const int off = __builtin_amdgcn_readfirstlane(offs[d]);
    const int n   = __builtin_amdgcn_readfirstlane(deg[d]);
    const int i32 = t & 31;
    const bool hiHalf = (t >= 32);
    const int g = ((i32 & 15) << 1) | (i32 >> 4); // swizzled col group
    const unsigned int voff = 8u * (unsigned)g;   // byte offset within a 256B row

    const uint2 urr = *(const uint2*)((const char*)hr + (size_t)d * 256 + voff);
    const half2v HR01 = __builtin_bit_cast(half2v, urr.x);
    const half2v HR23 = __builtin_bit_cast(half2v, urr.y);
    const uint2 apu = *(const uint2*)((const char*)att_h + voff);
    const half2v ap01 = __builtin_bit_cast(half2v, apu.x);
    const half2v ap23 = __builtin_bit_cast(half2v, apu.y);
    const half2v slope2 = { (_Float16)NSLOPE_GAT, (_Float16)NSLOPE_GAT };

    float l = 0.f, acc0 = 0.f, acc1 = 0.f, acc2 = 0.f, acc3 = 0.f;
    const char* __restrict__ hlb = (const char*)hl;

    auto load2 = [&](int sa, int sb) -> uint2 {
        int s = hiHalf ? sb : sa;
        return *(const uint2*)(hlb + (((unsigned int)s) << 8) + voff);
    };
    auto compute = [&](uint2 u, bool tailMask) {
        half2v A01 = __builtin_bit_cast(half2v, u.x);
        half2v A23 = __builtin_bit_cast(half2v, u.y);
        half2v z01 = A01 + HR01;
        half2v z23 = A23 + HR23;
        z01 = __builtin_elementwise_max(z01, z01 * slope2); // leaky_relu
        z23 = __builtin_elementwise_max(z23, z23 * slope2);
        float p = FDOT2(z01, ap01, FDOT2(z23, ap23, 0.f));
        p = row16_sum(p);                // per-head dot over the 16-lane row
        float w = EXP2(p);               // att pre-scaled by log2e
        if (tailMask && hiHalf) w = 0.f; // odd-degree tail: high half is a dup
        l += w;
        acc0 = fmaf(w, (float)A01[0], acc0);
        acc1 = fmaf(w, (float)A01[1], acc1);
        acc2 = fmaf(w, (float)A23[0], acc2);
        acc3 = fmaf(w, (float)A23[1], acc3);
    };

    int i = 0;
    for (; i + 4 <= n; i += 4) {
        int s0 = csr_src[off + i];
        int s1 = csr_src[off + i + 1];
        int s2 = csr_src[off + i + 2];
        int s3 = csr_src[off + i + 3];
        uint2 u0 = load2(s0, s1);
        uint2 u1 = load2(s2, s3);
        compute(u0, false);
        compute(u1, false);
    }
    if (i + 2 <= n) {
        int s0 = csr_src[off + i];
        int s1 = csr_src[off + i + 1];
        uint2 u0 = load2(s0, s1);
        compute(u0, false);
        i += 2;
    }
    if (i < n) {
        int s0 = csr_src[off + i];
        uint2 u0 = load2(s0, s0);
        compute(u0, true);
    }

    // merge the two edge-halves (same swizzled cols in both halves)
    l    += __shfl_xor(l, 32, 64);
    acc0 += __shfl_xor(acc0, 32, 64);
    acc1 += __shfl_xor(acc1, 32, 64);
    acc2 += __shfl_xor(acc2, 32, 64);
    acc3 += __shfl_xor(acc3, 32, 64);

    float inv = 1.f / (l + SM_EPS);
    const float4 bp = *(const float4*)(bias_perm + 4 * g);
    float v0 = fmaf(acc0, inv, bp.x);
    float v1 = fmaf(acc1, inv, bp.y);
    float v2 = fmaf(acc2, inv, bp.z);
    float v3 = fmaf(acc3, inv, bp.w);

    // LayerNorm over 128 features: each 32-lane half holds all 128 exactly once
    float sum = (v0 + v1) + (v2 + v3);
    #pragma unroll
    for (int o = 1; o <= 16; o <<= 1) sum += __shfl_xor(sum, o, 64);
    float mu = sum * (1.f / 128.f);
    float d0 = v0 - mu, d1 = v1 - mu, d2 = v2 - mu, d3 = v3 - mu;
    float sq = (d0 * d0 + d1 * d1) + (d2 * d2 + d3 * d3);
    #pragma unroll
    for (int o = 1; o <= 16; o <<= 1) sq += __shfl_xor(sq, o, 64);
    float rstd = rsqrtf(sq * (1.f / 128.f) + LN_EPS);

    const float4 ga = *(const float4*)(gamma_perm + 4 * g);
    const float4 be = *(const float4*)(beta_perm + 4 * g);
    float y0 = fmaf(d0 * rstd, ga.x, be.x);
    float y1 = fmaf(d1 * rstd, ga.y, be.y);
    float y2 = fmaf(d2 * rstd, ga.z, be.z);
    float y3 = fmaf(d3 * rstd, ga.w, be.w);
    y0 = fmaxf(y0, NSLOPE_ACT * y0);
    y1 = fmaxf(y1, NSLOPE_ACT * y1);
    y2 = fmaxf(y2, NSLOPE_ACT * y2);
    y3 = fmaxf(y3, NSLOPE_ACT * y3);

    // canonical col of slot j: c = 64*(g&1) + 16*j + (g>>1)
    if (!hiHalf) {
        const int h = g & 1, m = g >> 1;
        float* op = out + (size_t)d * HF + 64 * h + m;
        op[0]  = y0;
        op[16] = y1;
        op[32] = y2;
        op[48] = y3;
    }
}

// ---------------- launch ----------------
extern "C" void kernel_launch(void* const* d_in, const int* in_sizes, int n_in,
                              void* d_out, int out_size, void* d_ws, size_t ws_size,
                              hipStream_t stream) {
    const float* x     = (const float*)d_in[0];
    const int*   ei    = (const int*)d_in[1];
    const float* Wl    = (const float*)d_in[2];
    const float* bl    = (const float*)d_in[3];
    const float* Wr    = (const float*)d_in[4];
    const float* br    = (const float*)d_in[5];
    const float* att   = (const float*)d_in[6];
    const float* bias  = (const float*)d_in[7];
    const float* gamma = (const float*)d_in[8];
    const float* beta  = (const float*)d_in[9];
    float* out = (float*)d_out;

    char* ws = (char*)d_ws;
    unsigned short* hl = (unsigned short*)ws; ws += (size_t)Mc * HF * 2; // 25.6 MB (fp16)
    unsigned short* hr = (unsigned short*)ws; ws += (size_t)Mc * HF * 2; // 25.6 MB (fp16)
    unsigned short* Wb = (unsigned short*)ws; ws += 32768 * 2;           // 64 KB (bf16)
    _Float16* att_h   = (_Float16*)ws; ws += 512;                        // 128 fp16 (+pad)
    float* bias_perm  = (float*)ws; ws += 128 * sizeof(float);
    float* gamma_perm = (float*)ws; ws += 128 * sizeof(float);
    float* beta_perm  = (float*)ws; ws += 128 * sizeof(float);
    int* deg = (int*)ws;        ws += (size_t)Mc * sizeof(int);
    int* offs = (int*)ws;       ws += (size_t)Mc * sizeof(int);
    int* counts = (int*)ws;     ws += (size_t)PBLK * KBKT * sizeof(int); // 313 KB
    int* offmat = (int*)ws;     ws += (size_t)PBLK * KBKT * sizeof(int); // 313 KB
    int* colsum = (int*)ws;     ws += (KBKT + 1 + 64) * sizeof(int);
    int* bucketBase = (int*)ws; ws += (KBKT + 1 + 63) * sizeof(int);
    int* bar = (int*)ws;        ws += 64 * sizeof(int);
    unsigned int* pairs = (unsigned int*)ws; ws += (size_t)Ec * sizeof(int); // 3.2 MB
    int* csr_src = (int*)ws;    ws += (size_t)Ec * sizeof(int);              // 3.2 MB

    prep_w<<<128, 256, 0, stream>>>(Wl, Wr, att, bias, gamma, beta,
                                    Wb, att_h, bias_perm, gamma_perm, beta_perm,
                                    bar);
    gemm_csr<<<PBLK + GEMM_BLKS, 256, 0, stream>>>(
        x, Wb, bl, br, hl, hr, ei, counts, offmat, colsum, bucketBase,
        pairs, offs, deg, csr_src, bar);
    gat_fused<<<(Mc + 3) / 4, 256, 0, stream>>>(hl, hr, csr_src, offs, deg,
                                                att_h, bias_perm, gamma_perm,
                                                beta_perm, out);
}

// Round 6
// 214.057 us; speedup vs baseline: 1.4821x; 1.4821x over previous
//
#include <hip/hip_runtime.h>
#include <hip/hip_fp16.h>
#include <cmath>

// Problem constants (fixed by the reference)
constexpr int Bc = 2;
constexpr int Cc = 128;      // input channels
constexpr int Nc = 50000;
constexpr int Hh = 2;        // heads
constexpr int FHc = 64;      // features per head
constexpr int HF = Hh * FHc; // 128 = concat dim
constexpr int Mc = Bc * Nc;  // 100000 nodes
constexpr int Ec = 800000;   // edges

// CSR counting-sort geometry: fixed-capacity bucket windows -> NO global scan.
constexpr int PBLK = 64;                   // partition blocks (hist/scatter)
constexpr int CHUNK = Ec / PBLK;           // 12500 edges per partition
constexpr int KBKT = (Mc + 255) / 256;     // 391 buckets of 256 dst nodes
constexpr int CAP  = 4096;                 // bucket window capacity (max ~2200 @23 sigma)
constexpr int GEMM_BLKS = (Mc + 63) / 64;  // 1563 GEMM tiles

#define NSLOPE_GAT 0.2f
#define NSLOPE_ACT 0.01f
#define LN_EPS 1e-5f
#define SM_EPS 1e-16f
#define LOG2E 1.4426950408889634f

// h-storage is column-swizzled: c' = (c%16)*8 + c/16  (c = canonical col)
// inverse: c = (c'%8)*16 + c'/8. Head of swizzled col c': (c'&7) >= 4.
// => any aligned group of 4 consecutive swizzled cols (one uint2 of fp16)
//    lies entirely within ONE head: head = parity of the group index c'/4.

typedef __attribute__((ext_vector_type(8))) short short8;
typedef __attribute__((ext_vector_type(4))) float f32x4;
typedef _Float16 half2v __attribute__((ext_vector_type(2)));

__device__ inline unsigned short f2bf(float f) {
    union { float f; unsigned int i; } v; v.f = f;
    unsigned int r = v.i + 0x7fffu + ((v.i >> 16) & 1u);
    return (unsigned short)(r >> 16);
}

#if __has_builtin(__builtin_amdgcn_exp2f)
#define EXP2(x) __builtin_amdgcn_exp2f(x)
#else
#define EXP2(x) __expf((x) * 0.6931471805599453f)
#endif

#if __has_builtin(__builtin_amdgcn_fdot2)
#define FDOT2(a, b, c) __builtin_amdgcn_fdot2((a), (b), (c), false)
#else
__device__ inline float FDOT2(half2v a, half2v b, float c) {
    return fmaf((float)a[0], (float)b[0], fmaf((float)a[1], (float)b[1], c));
}
#endif

// One v_add_f32 + DPP row-rotate step (rows of 16 lanes, all lanes active).
template <int CTRL>
__device__ inline float dpp_add_step(float x) {
    int y = __builtin_amdgcn_update_dpp(0, __builtin_bit_cast(int, x),
                                        CTRL, 0xF, 0xF, false);
    return x + __builtin_bit_cast(float, y);
}
// Full-row (16-lane) sum via row_ror 1,2,4,8 — every lane ends with the total.
__device__ inline float row16_sum(float x) {
    x = dpp_add_step<0x121>(x); // row_ror:1
    x = dpp_add_step<0x122>(x); // row_ror:2
    x = dpp_add_step<0x124>(x); // row_ror:4
    x = dpp_add_step<0x128>(x); // row_ror:8
    return x;
}

// ---------------- D1: prep role (blocks 0..127) + bucket-histogram role
//                      (blocks 128..191). Roles fully independent. ----------
// Wb index = ((((mat*8+nt)*4+s)*64)+l)*8 + j ; holds W[k=32s+8*(l>>4)+j][n=16nt+(l&15)]
__global__ __launch_bounds__(256) void prep_hist(
    const float* __restrict__ Wl, const float* __restrict__ Wr,
    const float* __restrict__ att, const float* __restrict__ bias,
    const float* __restrict__ gamma, const float* __restrict__ beta,
    unsigned short* __restrict__ Wb, _Float16* __restrict__ att_h,
    float* __restrict__ bias_perm, float* __restrict__ gamma_perm,
    float* __restrict__ beta_perm,
    const int* __restrict__ ei, int* __restrict__ counts)
{
    const int tid = threadIdx.x;
    if (blockIdx.x >= 128) {
        // ---- bucket histogram of partition p's 12500 edge dsts (LDS atomics)
        __shared__ int hist[KBKT];
        const int p = blockIdx.x - 128;
        for (int k = tid; k < KBKT; k += 256) hist[k] = 0;
        __syncthreads();
        const int4* dsts = (const int4*)(ei + Ec + p * CHUNK);
        for (int i = tid; i < CHUNK / 4; i += 256) {
            int4 d = dsts[i];
            atomicAdd(&hist[d.x >> 8], 1);
            atomicAdd(&hist[d.y >> 8], 1);
            atomicAdd(&hist[d.z >> 8], 1);
            atomicAdd(&hist[d.w >> 8], 1);
        }
        __syncthreads();
        for (int k = tid; k < KBKT; k += 256) counts[p * KBKT + k] = hist[k];
        return;
    }
    // ---- prep role
    int i = blockIdx.x * 256 + tid;
    if (blockIdx.x == 0 && tid < 128) {
        int cp = tid;
        int c = (cp & 7) * 16 + (cp >> 3);          // canonical col of swizzled cp
        att_h[cp]      = (_Float16)(att[c] * LOG2E); // pre-scale for exp2
        bias_perm[cp]  = bias[c];
        gamma_perm[cp] = gamma[c];
        beta_perm[cp]  = beta[c];
    }
    int j = i & 7, l = (i >> 3) & 63, s = (i >> 9) & 3, nt = (i >> 11) & 7, mat = (i >> 14) & 1;
    int q = l >> 4, n15 = l & 15;
    int k = 32 * s + 8 * q + j;
    int n = 16 * nt + n15;
    const float* W = mat ? Wr : Wl;
    Wb[i] = f2bf(W[k * HF + n]);
}

// ---------------- D2: scatter role (blocks 0..63) + GEMM role (64..) --------
// Scatter: partition p's private window inside bucket k starts at
// k*CAP + sum_{p'<p} counts[p'][k]  (direct summation replaces the old scan).
// GEMM: unchanged round-4 structure (B-fragments in VGPRs, swizzled bf16
// A-tile in LDS, fp16 swizzled-col outputs). Roles are fully independent;
// the ~8us scatter hides under the ~45us GEMM.
__global__ __launch_bounds__(256, 3) void gemm_scatter(
    const float* __restrict__ x,
    const unsigned short* __restrict__ Wb,
    const float* __restrict__ bl, const float* __restrict__ br,
    unsigned short* __restrict__ hl, unsigned short* __restrict__ hr,
    const int* __restrict__ ei, const int* __restrict__ counts,
    unsigned int* __restrict__ pairs)
{
    __shared__ __align__(16) unsigned char smem[16384];
    const int tid = threadIdx.x;

    if (blockIdx.x < PBLK) {
        // =================== scatter role ===================
        const int p = blockIdx.x;
        int* cur = (int*)smem;
        for (int k = tid; k < KBKT; k += 256) {
            int base = k * CAP;
            for (int pp = 0; pp < p; ++pp) base += counts[pp * KBKT + k];
            cur[k] = base;
        }
        __syncthreads();
        const int4* srcs = (const int4*)(ei + p * CHUNK);
        const int4* dsts = (const int4*)(ei + Ec + p * CHUNK);
        for (int i = tid; i < CHUNK / 4; i += 256) {
            int4 s = srcs[i];
            int4 d = dsts[i];
            int p0 = atomicAdd(&cur[d.x >> 8], 1);
            pairs[p0] = ((unsigned)s.x << 8) | (unsigned)(d.x & 255);
            int p1 = atomicAdd(&cur[d.y >> 8], 1);
            pairs[p1] = ((unsigned)s.y << 8) | (unsigned)(d.y & 255);
            int p2 = atomicAdd(&cur[d.z >> 8], 1);
            pairs[p2] = ((unsigned)s.z << 8) | (unsigned)(d.z & 255);
            int p3 = atomicAdd(&cur[d.w >> 8], 1);
            pairs[p3] = ((unsigned)s.w << 8) | (unsigned)(d.w & 255);
        }
        return;
    }

    // =================== GEMM role ===================
    unsigned char* As = smem; // 16 KB: [row][2*k] bf16, byte ^= (row&7)<<4 swizzle
    const int r0 = (blockIdx.x - PBLK) * 64;
    const int l = tid & 63, w = tid >> 6;
    const int m15 = l & 15, q = l >> 4;

    // --- B fragments: 16 per wave, global->VGPR once (L2-hot, 64 KB total)
    const int matw = w >> 1, ntb = 4 * (w & 1);
    const short8* __restrict__ WB = (const short8*)Wb;
    short8 bfrag[4][4]; // [i = nt offset][s = k-step]
    #pragma unroll
    for (int i = 0; i < 4; ++i)
        #pragma unroll
        for (int s = 0; s < 4; ++s)
            bfrag[i][s] = WB[(((matw * 8 + ntb + i) * 4 + s) * 64) + l];

    // --- stage A: lane = row, 4 channels/thread/pass, dword loads
    {
        const int lrow = tid & 63;          // local row
        const int cg   = (tid >> 6) * 4;    // channel group base
        const int grow = r0 + lrow;
        const unsigned int swz = (unsigned)((lrow & 7) << 4);
        const bool valid = grow < Mc;
        int b = 0, n = grow;
        if (n >= Nc) { b = 1; n -= Nc; }
        const float* xb = x + (size_t)(b * Cc) * Nc + n;
        #pragma unroll
        for (int pp = 0; pp < 8; ++pp) {
            int c = cg + 16 * pp;
            float v0 = 0.f, v1 = 0.f, v2 = 0.f, v3 = 0.f;
            if (valid) {
                const float* xp = xb + (size_t)c * Nc;
                v0 = xp[0];
                v1 = xp[Nc];
                v2 = xp[2 * (size_t)Nc];
                v3 = xp[3 * (size_t)Nc];
            }
            unsigned int d0 = (unsigned)f2bf(v0) | ((unsigned)f2bf(v1) << 16);
            unsigned int d1 = (unsigned)f2bf(v2) | ((unsigned)f2bf(v3) << 16);
            unsigned int off = (unsigned)lrow * 256 + (((unsigned)(c * 2)) ^ swz);
            *(uint2*)(As + off) = make_uint2(d0, d1);
        }
    }
    __syncthreads();

    // --- bias (canonical col = 16*nt + m15) and output base
    const float* bsrc = matw ? br : bl;
    unsigned short* __restrict__ hdst = matw ? hr : hl;
    float bv[4];
    #pragma unroll
    for (int i = 0; i < 4; ++i) bv[i] = bsrc[16 * (ntb + i) + m15];

    const unsigned int rswz = (unsigned)((m15 & 7) << 4);
    #pragma unroll
    for (int mt = 0; mt < 4; ++mt) {
        short8 af[4];
        #pragma unroll
        for (int s = 0; s < 4; ++s) {
            unsigned int off = (unsigned)(16 * mt + m15) * 256 +
                               (((unsigned)(64 * s + 16 * q)) ^ rswz);
            af[s] = *(const short8*)(As + off);
        }
        f32x4 acc[4];
        #pragma unroll
        for (int i = 0; i < 4; ++i) acc[i] = (f32x4)(0.f);
        #pragma unroll
        for (int s = 0; s < 4; ++s)
            #pragma unroll
            for (int i = 0; i < 4; ++i)
                acc[i] = __builtin_amdgcn_mfma_f32_16x16x32_bf16(af[s], bfrag[i][s], acc[i], 0, 0, 0);

        // D: row = 4q+reg (tile-local), canonical col = 16*(ntb+i)+m15
        // swizzled col' = m15*8 + ntb + i  ->  uint2 (4 fp16) per row
        #pragma unroll
        for (int reg = 0; reg < 4; ++reg) {
            int rD = r0 + 16 * mt + 4 * q + reg;
            if (rD < Mc) {
                half2v hlo = { (_Float16)(acc[0][reg] + bv[0]),
                               (_Float16)(acc[1][reg] + bv[1]) };
                half2v hhi = { (_Float16)(acc[2][reg] + bv[2]),
                               (_Float16)(acc[3][reg] + bv[3]) };
                *(uint2*)(hdst + (size_t)rD * HF + m15 * 8 + ntb) =
                    make_uint2(__builtin_bit_cast(unsigned int, hlo),
                               __builtin_bit_cast(unsigned int, hhi));
            }
        }
    }
}

// ---------------- D3: per-bucket node histogram + scan -> offs/deg/csr_src --
// One block per bucket, window base = b*CAP (no global scan anywhere).
__global__ __launch_bounds__(256) void bucket_csr(const unsigned int* __restrict__ pairs,
                                                  const int* __restrict__ counts,
                                                  int* __restrict__ offs,
                                                  int* __restrict__ deg,
                                                  int* __restrict__ csr_src)
{
    __shared__ int cnt[256];
    __shared__ int scn[256];
    __shared__ int cur[256];
    __shared__ int ecnt_s;
    const int b = blockIdx.x, tid = threadIdx.x;
    const int base = b * CAP;
    // bucket edge count = sum over the 64 partitions (one wave reduces it)
    if (tid < 64) {
        int v = counts[tid * KBKT + b];
        #pragma unroll
        for (int o = 32; o; o >>= 1) v += __shfl_xor(v, o, 64);
        if (tid == 0) ecnt_s = v;
    }
    cnt[tid] = 0;
    __syncthreads();
    const int ecnt = ecnt_s;
    for (int i = tid; i < ecnt; i += 256)
        atomicAdd(&cnt[pairs[base + i] & 255u], 1);
    __syncthreads();
    int c = cnt[tid];
    scn[tid] = c;
    __syncthreads();
    for (int off = 1; off < 256; off <<= 1) {
        int v = (tid >= off) ? scn[tid - off] : 0;
        __syncthreads();
        scn[tid] += v;
        __syncthreads();
    }
    int excl = scn[tid] - c;
    int node = (b << 8) + tid;
    if (node < Mc) {
        offs[node] = base + excl;
        deg[node] = c;
    }
    cur[tid] = base + excl;
    __syncthreads();
    for (int i = tid; i < ecnt; i += 256) {
        unsigned pr = pairs[base + i];
        int pos = atomicAdd(&cur[pr & 255u], 1);
        csr_src[pos] = (int)(pr >> 8);
    }
}

// ---------------- D4: fully fused per-node logits+softmax+aggregate+LN ------
// One wave per node, TWO edges per iteration (one per 32-lane half).
// Lane t: half = t>>5 (edge select), i32 = t&31. Lane owns swizzled col
// GROUP g = ((i32&15)<<1)|(i32>>4) -> cols 4g..4g+3, all in head g&1 = i32>>4.
// So each head's 64 features live in ONE contiguous 16-lane DPP row: the
// per-head dot reduction is 4 v_add_f32+row_ror DPP ops -- no LDS, no
// shuffles in the inner loop. fp16 storage: packed v_pk_add/mul/max_f16 +
// v_dot2_f32_f16 for the dot; v_fma_mix_f32 for the f32 accumulate.
__global__ __launch_bounds__(256) void gat_fused(
    const unsigned short* __restrict__ hl, const unsigned short* __restrict__ hr,
    const int* __restrict__ csr_src,
    const int* __restrict__ offs, const int* __restrict__ deg,
    const _Float16* __restrict__ att_h, const float* __restrict__ bias_perm,
    const float* __restrict__ gamma_perm, const float* __restrict__ beta_perm,
    float* __restrict__ out)
{
    const int wv = threadIdx.x >> 6;
    const int t  = threadIdx.x & 63;
    const int d  = blockIdx.x * 4 + wv;
    if (d >= Mc) return;
    const int off = __builtin_amdgcn_readfirstlane(offs[d]);
    const int n   = __builtin_amdgcn_readfirstlane(deg[d]);
    const int i32 = t & 31;
    const bool hiHalf = (t >= 32);
    const int g = ((i32 & 15) << 1) | (i32 >> 4); // swizzled col group
    const unsigned int voff = 8u * (unsigned)g;   // byte offset within a 256B row

    const uint2 urr = *(const uint2*)((const char*)hr + (size_t)d * 256 + voff);
    const half2v HR01 = __builtin_bit_cast(half2v, urr.x);
    const half2v HR23 = __builtin_bit_cast(half2v, urr.y);
    const uint2 apu = *(const uint2*)((const char*)att_h + voff);
    const half2v ap01 = __builtin_bit_cast(half2v, apu.x);
    const half2v ap23 = __builtin_bit_cast(half2v, apu.y);
    const half2v slope2 = { (_Float16)NSLOPE_GAT, (_Float16)NSLOPE_GAT };

    float l = 0.f, acc0 = 0.f, acc1 = 0.f, acc2 = 0.f, acc3 = 0.f;
    const char* __restrict__ hlb = (const char*)hl;

    auto load2 = [&](int sa, int sb) -> uint2 {
        int s = hiHalf ? sb : sa;
        return *(const uint2*)(hlb + (((unsigned int)s) << 8) + voff);
    };
    auto compute = [&](uint2 u, bool tailMask) {
        half2v A01 = __builtin_bit_cast(half2v, u.x);
        half2v A23 = __builtin_bit_cast(half2v, u.y);
        half2v z01 = A01 + HR01;
        half2v z23 = A23 + HR23;
        z01 = __builtin_elementwise_max(z01, z01 * slope2); // leaky_relu
        z23 = __builtin_elementwise_max(z23, z23 * slope2);
        float p = FDOT2(z01, ap01, FDOT2(z23, ap23, 0.f));
        p = row16_sum(p);                // per-head dot over the 16-lane row
        float w = EXP2(p);               // att pre-scaled by log2e
        if (tailMask && hiHalf) w = 0.f; // odd-degree tail: high half is a dup
        l += w;
        acc0 = fmaf(w, (float)A01[0], acc0);
        acc1 = fmaf(w, (float)A01[1], acc1);
        acc2 = fmaf(w, (float)A23[0], acc2);
        acc3 = fmaf(w, (float)A23[1], acc3);
    };

    int i = 0;
    for (; i + 4 <= n; i += 4) {
        int s0 = csr_src[off + i];
        int s1 = csr_src[off + i + 1];
        int s2 = csr_src[off + i + 2];
        int s3 = csr_src[off + i + 3];
        uint2 u0 = load2(s0, s1);
        uint2 u1 = load2(s2, s3);
        compute(u0, false);
        compute(u1, false);
    }
    if (i + 2 <= n) {
        int s0 = csr_src[off + i];
        int s1 = csr_src[off + i + 1];
        uint2 u0 = load2(s0, s1);
        compute(u0, false);
        i += 2;
    }
    if (i < n) {
        int s0 = csr_src[off + i];
        uint2 u0 = load2(s0, s0);
        compute(u0, true);
    }

    // merge the two edge-halves (same swizzled cols in both halves)
    l    += __shfl_xor(l, 32, 64);
    acc0 += __shfl_xor(acc0, 32, 64);
    acc1 += __shfl_xor(acc1, 32, 64);
    acc2 += __shfl_xor(acc2, 32, 64);
    acc3 += __shfl_xor(acc3, 32, 64);

    float inv = 1.f / (l + SM_EPS);
    const float4 bp = *(const float4*)(bias_perm + 4 * g);
    float v0 = fmaf(acc0, inv, bp.x);
    float v1 = fmaf(acc1, inv, bp.y);
    float v2 = fmaf(acc2, inv, bp.z);
    float v3 = fmaf(acc3, inv, bp.w);

    // LayerNorm over 128 features: each 32-lane half holds all 128 exactly once
    float sum = (v0 + v1) + (v2 + v3);
    #pragma unroll
    for (int o = 1; o <= 16; o <<= 1) sum += __shfl_xor(sum, o, 64);
    float mu = sum * (1.f / 128.f);
    float d0 = v0 - mu, d1 = v1 - mu, d2 = v2 - mu, d3 = v3 - mu;
    float sq = (d0 * d0 + d1 * d1) + (d2 * d2 + d3 * d3);
    #pragma unroll
    for (int o = 1; o <= 16; o <<= 1) sq += __shfl_xor(sq, o, 64);
    float rstd = rsqrtf(sq * (1.f / 128.f) + LN_EPS);

    const float4 ga = *(const float4*)(gamma_perm + 4 * g);
    const float4 be = *(const float4*)(beta_perm + 4 * g);
    float y0 = fmaf(d0 * rstd, ga.x, be.x);
    float y1 = fmaf(d1 * rstd, ga.y, be.y);
    float y2 = fmaf(d2 * rstd, ga.z, be.z);
    float y3 = fmaf(d3 * rstd, ga.w, be.w);
    y0 = fmaxf(y0, NSLOPE_ACT * y0);
    y1 = fmaxf(y1, NSLOPE_ACT * y1);
    y2 = fmaxf(y2, NSLOPE_ACT * y2);
    y3 = fmaxf(y3, NSLOPE_ACT * y3);

    // canonical col of slot j: c = 64*(g&1) + 16*j + (g>>1)
    if (!hiHalf) {
        const int h = g & 1, m = g >> 1;
        float* op = out + (size_t)d * HF + 64 * h + m;
        op[0]  = y0;
        op[16] = y1;
        op[32] = y2;
        op[48] = y3;
    }
}

// ---------------- launch ----------------
extern "C" void kernel_launch(void* const* d_in, const int* in_sizes, int n_in,
                              void* d_out, int out_size, void* d_ws, size_t ws_size,
                              hipStream_t stream) {
    const float* x     = (const float*)d_in[0];
    const int*   ei    = (const int*)d_in[1];
    const float* Wl    = (const float*)d_in[2];
    const float* bl    = (const float*)d_in[3];
    const float* Wr    = (const float*)d_in[4];
    const float* br    = (const float*)d_in[5];
    const float* att   = (const float*)d_in[6];
    const float* bias  = (const float*)d_in[7];
    const float* gamma = (const float*)d_in[8];
    const float* beta  = (const float*)d_in[9];
    float* out = (float*)d_out;

    char* ws = (char*)d_ws;
    unsigned short* hl = (unsigned short*)ws; ws += (size_t)Mc * HF * 2; // 25.6 MB (fp16)
    unsigned short* hr = (unsigned short*)ws; ws += (size_t)Mc * HF * 2; // 25.6 MB (fp16)
    unsigned short* Wb = (unsigned short*)ws; ws += 32768 * 2;           // 64 KB (bf16)
    _Float16* att_h   = (_Float16*)ws; ws += 512;                        // 128 fp16 (+pad)
    float* bias_perm  = (float*)ws; ws += 128 * sizeof(float);
    float* gamma_perm = (float*)ws; ws += 128 * sizeof(float);
    float* beta_perm  = (float*)ws; ws += 128 * sizeof(float);
    int* deg = (int*)ws;        ws += (size_t)Mc * sizeof(int);
    int* offs = (int*)ws;       ws += (size_t)Mc * sizeof(int);
    int* counts = (int*)ws;     ws += (size_t)PBLK * KBKT * sizeof(int);   // 100 KB
    unsigned int* pairs = (unsigned int*)ws; ws += (size_t)KBKT * CAP * 4; // 6.4 MB
    int* csr_src = (int*)ws;    ws += (size_t)KBKT * CAP * 4;              // 6.4 MB

    prep_hist<<<128 + PBLK, 256, 0, stream>>>(Wl, Wr, att, bias, gamma, beta,
                                              Wb, att_h, bias_perm, gamma_perm,
                                              beta_perm, ei, counts);
    gemm_scatter<<<PBLK + GEMM_BLKS, 256, 0, stream>>>(x, Wb, bl, br, hl, hr,
                                                       ei, counts, pairs);
    bucket_csr<<<KBKT, 256, 0, stream>>>(pairs, counts, offs, deg, csr_src);
    gat_fused<<<(Mc + 3) / 4, 256, 0, stream>>>(hl, hr, csr_src, offs, deg,
                                                att_h, bias_perm, gamma_perm,
                                                beta_perm, out);
}